// Round 5
// baseline (964.191 us; speedup 1.0000x reference)
//
#include <hip/hip_runtime.h>
#include <math.h>

typedef float f32x4 __attribute__((ext_vector_type(4)));
typedef short short8 __attribute__((ext_vector_type(8)));
typedef unsigned short u16;

#define BB 32
#define CC 192
#define HEADS 6
#define NN 64
#define HID 768
#define NTOK (BB * 64 * 64)
#define SCALE 0.17677669529663687f

#define MFMA(a, b, c) __builtin_amdgcn_mfma_f32_16x16x32_bf16(a, b, c, 0, 0, 0)

__device__ __forceinline__ u16 f2bf(float f) {
  union { float f; unsigned int u; } cv;
  cv.f = f;
  unsigned int u = cv.u;
  u += 0x7fffu + ((u >> 16) & 1u);
  return (u16)(u >> 16);
}

__device__ __forceinline__ f32x4 vzero() {
  f32x4 v;
  v[0] = 0.f; v[1] = 0.f; v[2] = 0.f; v[3] = 0.f;
  return v;
}

// A-style fragment read from swizzled LDS bf16 matrix. pitch in elements.
__device__ __forceinline__ short8 ldsA(const u16* M, int pitch, int r0, int k0, int lane) {
  const int r = r0 + (lane & 15);
  const int cb = ((k0 + ((lane >> 4) << 3)) << 1) ^ ((r & 7) << 4);
  return *(const short8*)(M + r * pitch + (cb >> 1));
}

// B fragment from global K-contiguous (transposed) bf16 weight [N][K].
__device__ __forceinline__ short8 glbB(const u16* W, int pitch, int n0, int k0, int lane) {
  const int n = n0 + (lane & 15);
  return *(const short8*)(W + (size_t)n * pitch + k0 + ((lane >> 4) << 3));
}

// ---------------------------------------------------------------------------
// K0: convert + transpose weights to bf16 K-contiguous tables in ws
// ---------------------------------------------------------------------------
__global__ __launch_bounds__(256) void prep_kernel(
    const float* __restrict__ qkvw, const float* __restrict__ pw,
    const float* __restrict__ w1, const float* __restrict__ w2,
    u16* __restrict__ wqkvT, u16* __restrict__ projT,
    u16* __restrict__ w1T, u16* __restrict__ w2T) {
  const int id = blockIdx.x * 256 + threadIdx.x;
  if (id < 576 * 192) { const int n = id / 192, k = id - n * 192; wqkvT[id] = f2bf(qkvw[k * 576 + n]); }
  if (id < 192 * 192) { const int n = id / 192, k = id - n * 192; projT[id] = f2bf(pw[k * 192 + n]); }
  if (id < 768 * 192) { const int n = id / 192, k = id - n * 192; w1T[id] = f2bf(w1[k * 768 + n]); }
  if (id < 192 * 768) { const int n = id / 768, k = id - n * 768; w2T[id] = f2bf(w2[k * 192 + n]); }
}

// ---------------------------------------------------------------------------
// K1: LN1 + cyclic shift (-4,-4) + window partition -> hw bf16 (B*nW, 64, 192)
// ---------------------------------------------------------------------------
__global__ __launch_bounds__(256) void ln1_kernel(
    const float* __restrict__ x, const float* __restrict__ gamma,
    const float* __restrict__ beta, u16* __restrict__ hw) {
  const int gid = blockIdx.x * blockDim.x + threadIdx.x;
  const int T = gid >> 6;
  const int lane = threadIdx.x & 63;
  if (T >= NTOK) return;
  const int g = T >> 6;
  const int n = T & 63;
  const int b = g >> 6;
  const int w = g & 63;
  const int wr = w >> 3, wc = w & 7;
  const int sr = ((wr << 3) + (n >> 3) + 4) & 63;
  const int sc = ((wc << 3) + (n & 7) + 4) & 63;
  const float* xp = x + ((size_t)b * 4096 + sr * 64 + sc) * CC;
  const float v0 = xp[lane], v1 = xp[lane + 64], v2 = xp[lane + 128];
  float s = v0 + v1 + v2;
  float sq = v0 * v0 + v1 * v1 + v2 * v2;
#pragma unroll
  for (int off = 1; off < 64; off <<= 1) {
    s += __shfl_xor(s, off);
    sq += __shfl_xor(sq, off);
  }
  const float mean = s * (1.0f / 192.0f);
  const float var = sq * (1.0f / 192.0f) - mean * mean;
  const float rstd = rsqrtf(var + 1e-5f);
  u16* op = hw + (size_t)T * CC;
  op[lane]       = f2bf((v0 - mean) * rstd * gamma[lane]       + beta[lane]);
  op[lane + 64]  = f2bf((v1 - mean) * rstd * gamma[lane + 64]  + beta[lane + 64]);
  op[lane + 128] = f2bf((v2 - mean) * rstd * gamma[lane + 128] + beta[lane + 128]);
}

// ---------------------------------------------------------------------------
// K2: windowed attention, MFMA. 1 block = 1 window, 8 waves.
// In-register softmax; per-head loop is barrier-free (each wave only touches
// its own 16 rows of P).
// ---------------------------------------------------------------------------
__global__ __launch_bounds__(512) void attn_kernel(
    u16* __restrict__ hw, const u16* __restrict__ wqkvT,
    const float* __restrict__ qkvb, const float* __restrict__ rpb) {
  __shared__ u16 Xs[64 * 192];
  __shared__ u16 Qs[64 * 192];
  __shared__ u16 Ks[64 * 192];
  __shared__ u16 Vt[192 * 64];     // [channel][token]
  __shared__ u16 Pb[2][64 * 64];

  const int g = blockIdx.x;
  const int t = threadIdx.x;
  const int w = t >> 6;
  const int lane = t & 63;
  const int wr = (g >> 3) & 7, wc = g & 7;
  u16* win = hw + (size_t)g * (64 * 192);

  // stage window into Xs (swizzled), 16B units
#pragma unroll
  for (int u = 0; u < 3; ++u) {
    const int d = (t * 3 + u) << 4;
    const int row = d / 384;
    const int cb = d - row * 384;
    const short8 v = *(const short8*)((const char*)win + d);
    *(short8*)((char*)Xs + row * 384 + (cb ^ ((row & 7) << 4))) = v;
  }
  __syncthreads();

  // ---- QKV GEMM: 64x192 @ 192x576 ----
  const int ntbeg = (w < 4) ? w * 5 : 20 + (w - 4) * 4;
  const int ntcnt = (w < 4) ? 5 : 4;
  f32x4 acc[5][4];
#pragma unroll
  for (int p = 0; p < 5; ++p)
#pragma unroll
    for (int m = 0; m < 4; ++m) acc[p][m] = vzero();
#pragma unroll
  for (int kk = 0; kk < 6; ++kk) {
    const int k0 = kk << 5;
    short8 a[4];
#pragma unroll
    for (int m = 0; m < 4; ++m) a[m] = ldsA(Xs, 192, m << 4, k0, lane);
#pragma unroll
    for (int p = 0; p < 5; ++p) {
      int nt = ntbeg + p;
      if (nt > 35) nt = 35;  // waves 4-7 duplicate last tile (discarded)
      const short8 b = glbB(wqkvT, 192, nt << 4, k0, lane);
#pragma unroll
      for (int m = 0; m < 4; ++m) acc[p][m] = MFMA(a[m], b, acc[p][m]);
    }
  }
#pragma unroll
  for (int p = 0; p < 5; ++p) {
    if (p < ntcnt) {
      const int cg = ((ntbeg + p) << 4) + (lane & 15);
      const float bias = qkvb[cg];
#pragma unroll
      for (int m = 0; m < 4; ++m) {
#pragma unroll
        for (int i = 0; i < 4; ++i) {
          const int r = (m << 4) + ((lane >> 4) << 2) + i;
          const float val = acc[p][m][i] + bias;
          if (cg < 192) {
            const int cb = (cg << 1) ^ ((r & 7) << 4);
            Qs[r * 192 + (cb >> 1)] = f2bf(val * SCALE);
          } else if (cg < 384) {
            const int cb = ((cg - 192) << 1) ^ ((r & 7) << 4);
            Ks[r * 192 + (cb >> 1)] = f2bf(val);
          } else {
            const int vc = cg - 384;
            const int cb = (r << 1) ^ ((vc & 7) << 4);
            Vt[vc * 64 + (cb >> 1)] = f2bf(val);
          }
        }
      }
    }
  }
  __syncthreads();

  // ---- per-head: scores -> in-reg softmax -> PV. wave = (s, mt). ----
  const int s = w >> 2;
  const int mt = w & 3;
  u16* P = Pb[s];
  const int cbase = lane & 15;
  for (int hh = 0; hh < 3; ++hh) {
    const int h = s * 3 + hh;
    const short8 aq = ldsA(Qs, 192, mt << 4, h << 5, lane);
    f32x4 d[4];
#pragma unroll
    for (int kb = 0; kb < 4; ++kb) {
      const short8 bk = ldsA(Ks, 192, kb << 4, h << 5, lane);
      d[kb] = MFMA(aq, bk, vzero());
      const int c = (kb << 4) + cbase;
      const int i2 = c >> 3, j2 = c & 7;
      const int gr2 = (wr << 3) + i2, gc2 = (wc << 3) + j2;
      const int lab2 = (gr2 < 56 ? 0 : (gr2 < 60 ? 1 : 2)) * 3 +
                       (gc2 < 56 ? 0 : (gc2 < 60 ? 1 : 2));
#pragma unroll
      for (int i = 0; i < 4; ++i) {
        const int r = (mt << 4) + ((lane >> 4) << 2) + i;
        const int i1 = r >> 3, j1 = r & 7;
        const int gr1 = (wr << 3) + i1, gc1 = (wc << 3) + j1;
        const int lab1 = (gr1 < 56 ? 0 : (gr1 < 60 ? 1 : 2)) * 3 +
                         (gc1 < 56 ? 0 : (gc1 < 60 ? 1 : 2));
        float v = d[kb][i] + rpb[((i1 - i2 + 7) * 15 + (j1 - j2 + 7)) * HEADS + h];
        if (lab1 != lab2) v -= 100.f;
        d[kb][i] = v;
      }
    }
    // in-register softmax: row r spread over the 16-lane group (lane&15)
    float mx[4], sum[4];
#pragma unroll
    for (int i = 0; i < 4; ++i) {
      mx[i] = fmaxf(fmaxf(d[0][i], d[1][i]), fmaxf(d[2][i], d[3][i]));
    }
#pragma unroll
    for (int msk = 1; msk < 16; msk <<= 1) {
#pragma unroll
      for (int i = 0; i < 4; ++i) mx[i] = fmaxf(mx[i], __shfl_xor(mx[i], msk));
    }
#pragma unroll
    for (int i = 0; i < 4; ++i) sum[i] = 0.f;
#pragma unroll
    for (int kb = 0; kb < 4; ++kb) {
#pragma unroll
      for (int i = 0; i < 4; ++i) {
        const float e = __expf(d[kb][i] - mx[i]);
        d[kb][i] = e;
        sum[i] += e;
      }
    }
#pragma unroll
    for (int msk = 1; msk < 16; msk <<= 1) {
#pragma unroll
      for (int i = 0; i < 4; ++i) sum[i] += __shfl_xor(sum[i], msk);
    }
#pragma unroll
    for (int kb = 0; kb < 4; ++kb) {
      const int c = (kb << 4) + cbase;
#pragma unroll
      for (int i = 0; i < 4; ++i) {
        const int r = (mt << 4) + ((lane >> 4) << 2) + i;
        const int cb = (c << 1) ^ ((r & 7) << 4);
        P[r * 64 + (cb >> 1)] = f2bf(d[kb][i] / sum[i]);
      }
    }
    // PV: O rows 16mt..+15, cols h*32 + nb*16 (reads only this wave's P rows)
#pragma unroll
    for (int nb = 0; nb < 2; ++nb) {
      f32x4 o = vzero();
#pragma unroll
      for (int ks = 0; ks < 2; ++ks) {
        const short8 ap = ldsA(P, 64, mt << 4, ks << 5, lane);
        const short8 bv = ldsA(Vt, 64, (h << 5) + (nb << 4), ks << 5, lane);
        o = MFMA(ap, bv, o);
      }
      const int c = (h << 5) + (nb << 4) + (lane & 15);
#pragma unroll
      for (int i = 0; i < 4; ++i) {
        const int r = (mt << 4) + ((lane >> 4) << 2) + i;
        win[r * 192 + c] = f2bf(o[i]);
      }
    }
  }
}

// ---------------------------------------------------------------------------
// K3: proj GEMM + bias + reverse shift scatter + residual -> out (fp32)
// ---------------------------------------------------------------------------
__global__ __launch_bounds__(256) void proj_kernel(
    const u16* __restrict__ hw, const u16* __restrict__ projT,
    const float* __restrict__ pb, const float* __restrict__ x,
    float* __restrict__ out) {
  __shared__ u16 Os[64 * 192];
  const int g = blockIdx.x;
  const int t = threadIdx.x;
  const int w = t >> 6;
  const int lane = t & 63;
  const int b_ = g >> 6;
  const int wr = (g >> 3) & 7, wc = g & 7;
  const u16* win = hw + (size_t)g * (64 * 192);
#pragma unroll
  for (int u = 0; u < 6; ++u) {
    const int d = (t * 6 + u) << 4;
    const int row = d / 384;
    const int cb = d - row * 384;
    const short8 v = *(const short8*)((const char*)win + d);
    *(short8*)((char*)Os + row * 384 + (cb ^ ((row & 7) << 4))) = v;
  }
  __syncthreads();
#pragma unroll
  for (int gi = 0; gi < 2; ++gi) {
    f32x4 acc[6];
#pragma unroll
    for (int p = 0; p < 6; ++p) acc[p] = vzero();
#pragma unroll
    for (int kk = 0; kk < 6; ++kk) {
      const int k0 = kk << 5;
      const short8 a = ldsA(Os, 192, w << 4, k0, lane);
#pragma unroll
      for (int p = 0; p < 6; ++p) {
        const short8 b = glbB(projT, 192, (gi * 6 + p) << 4, k0, lane);
        acc[p] = MFMA(a, b, acc[p]);
      }
    }
#pragma unroll
    for (int p = 0; p < 6; ++p) {
      const int col = ((gi * 6 + p) << 4) + (lane & 15);
      const float bias = pb[col];
#pragma unroll
      for (int i = 0; i < 4; ++i) {
        const int r = (w << 4) + ((lane >> 4) << 2) + i;
        const int dr = ((wr << 3) + (r >> 3) + 4) & 63;
        const int dc = ((wc << 3) + (r & 7) + 4) & 63;
        const size_t dst = ((size_t)b_ * 4096 + dr * 64 + dc) * 192 + col;
        out[dst] = x[dst] + acc[p][i] + bias;
      }
    }
  }
}

// ---------------------------------------------------------------------------
// K4: LN2 + fc1 + GELU + fc2 + residual. 64 tokens/block, 8 waves.
// fc1 N split into 2 phases (Hs = 64x384 only); fc2 split-K accumulates in
// registers across the phases. LDS 73.7 KB -> 2 blocks/CU.
// ---------------------------------------------------------------------------
__global__ __launch_bounds__(512, 4) void mlp_kernel(
    float* __restrict__ out, const float* __restrict__ g2,
    const float* __restrict__ bn2, const u16* __restrict__ w1T,
    const float* __restrict__ b1, const u16* __restrict__ w2T,
    const float* __restrict__ bo) {
  __shared__ u16 Xn[64 * 192];
  __shared__ u16 Hs[64 * 384];
  const size_t T0 = (size_t)blockIdx.x * 64;
  const int t = threadIdx.x;
  const int w = t >> 6;
  const int lane = t & 63;

  {  // LN2: 8 lanes per token, 24 ch each
    const int tok = t >> 3;
    const int ch0 = (t & 7) * 24;
    const float* xp = out + (T0 + tok) * 192 + ch0;
    float v[24];
    float s = 0.f, sq = 0.f;
#pragma unroll
    for (int q = 0; q < 6; ++q) {
      const float4 f4 = *(const float4*)(xp + q * 4);
      v[q * 4 + 0] = f4.x; v[q * 4 + 1] = f4.y;
      v[q * 4 + 2] = f4.z; v[q * 4 + 3] = f4.w;
    }
#pragma unroll
    for (int q = 0; q < 24; ++q) { s += v[q]; sq += v[q] * v[q]; }
#pragma unroll
    for (int msk = 1; msk < 8; msk <<= 1) {
      s += __shfl_xor(s, msk);
      sq += __shfl_xor(sq, msk);
    }
    const float mean = s * (1.f / 192.f);
    const float var = sq * (1.f / 192.f) - mean * mean;
    const float rstd = rsqrtf(var + 1e-5f);
#pragma unroll
    for (int q = 0; q < 12; ++q) {
      const int ch = ch0 + q * 2;
      const float a0 = (v[q * 2] - mean) * rstd * g2[ch] + bn2[ch];
      const float a1 = (v[q * 2 + 1] - mean) * rstd * g2[ch + 1] + bn2[ch + 1];
      const unsigned int pk = (unsigned int)f2bf(a0) | ((unsigned int)f2bf(a1) << 16);
      const int cb = (ch << 1) ^ ((tok & 7) << 4);
      *(unsigned int*)&Xn[tok * 192 + (cb >> 1)] = pk;
    }
  }
  __syncthreads();

  const int mt = w & 3;
  const int half = w >> 2;
  f32x4 acc2[6];
#pragma unroll
  for (int p = 0; p < 6; ++p) acc2[p] = vzero();

#pragma unroll
  for (int ph = 0; ph < 2; ++ph) {
    // ---- fc1 phase ph: hidden cols [ph*384 + half*192 + p*16] ----
    {
      f32x4 acc[12];
#pragma unroll
      for (int p = 0; p < 12; ++p) acc[p] = vzero();
#pragma unroll
      for (int kk = 0; kk < 6; ++kk) {
        const int k0 = kk << 5;
        const short8 a = ldsA(Xn, 192, mt << 4, k0, lane);
#pragma unroll
        for (int p = 0; p < 12; ++p) {
          const int nt = ph * 24 + half * 12 + p;
          const short8 b = glbB(w1T, 192, nt << 4, k0, lane);
          acc[p] = MFMA(a, b, acc[p]);
        }
      }
#pragma unroll
      for (int p = 0; p < 12; ++p) {
        const int colg = ((ph * 24 + half * 12 + p) << 4) + (lane & 15);
        const int lcol = colg - ph * 384;   // 0..383 within Hs
        const float bias = b1[colg];
#pragma unroll
        for (int i = 0; i < 4; ++i) {
          const int r = (mt << 4) + ((lane >> 4) << 2) + i;
          const float hv = acc[p][i] + bias;
          const float ge = 0.5f * hv * (1.0f + erff(hv * 0.70710678118654752f));
          const int cb = (lcol << 1) ^ ((r & 7) << 4);
          Hs[r * 384 + (cb >> 1)] = f2bf(ge);
        }
      }
    }
    __syncthreads();
    // ---- fc2 partial: K slice [ph*384, ph*384+384) ----
#pragma unroll
    for (int kk = 0; kk < 12; ++kk) {
      const int k0 = kk << 5;
      const short8 a = ldsA(Hs, 384, mt << 4, k0, lane);
#pragma unroll
      for (int p = 0; p < 6; ++p) {
        const int nt = half * 6 + p;
        const short8 b = glbB(w2T, 768, nt << 4, ph * 384 + k0, lane);
        acc2[p] = MFMA(a, b, acc2[p]);
      }
    }
    if (ph == 0) __syncthreads();  // before Hs overwrite in phase 1
  }

  // ---- fc2 epilogue + residual ----
#pragma unroll
  for (int p = 0; p < 6; ++p) {
    const int col = ((half * 6 + p) << 4) + (lane & 15);
    const float bias = bo[col];
#pragma unroll
    for (int i = 0; i < 4; ++i) {
      const int r = (mt << 4) + ((lane >> 4) << 2) + i;
      float* op = out + (T0 + r) * 192 + col;
      *op = *op + acc2[p][i] + bias;
    }
  }
}

// ---------------------------------------------------------------------------
extern "C" void kernel_launch(void* const* d_in, const int* in_sizes, int n_in,
                              void* d_out, int out_size, void* d_ws, size_t ws_size,
                              hipStream_t stream) {
  const float* x    = (const float*)d_in[0];
  const float* n1g  = (const float*)d_in[1];
  const float* n1b  = (const float*)d_in[2];
  const float* qkvw = (const float*)d_in[3];
  const float* qkvb = (const float*)d_in[4];
  const float* rpb  = (const float*)d_in[5];
  const float* pw   = (const float*)d_in[6];
  const float* pb   = (const float*)d_in[7];
  const float* n2g  = (const float*)d_in[8];
  const float* n2b  = (const float*)d_in[9];
  const float* w1   = (const float*)d_in[10];
  const float* b1   = (const float*)d_in[11];
  const float* w2   = (const float*)d_in[12];
  const float* b2   = (const float*)d_in[13];
  float* out = (float*)d_out;

  u16* hw    = (u16*)d_ws;                       // 131072*192 bf16 = 50.3 MB
  u16* wqkvT = hw + (size_t)131072 * 192;        // [576][192]
  u16* projT = wqkvT + 576 * 192;                // [192][192]
  u16* w1T   = projT + 192 * 192;                // [768][192]
  u16* w2T   = w1T + 768 * 192;                  // [192][768]

  prep_kernel<<<576, 256, 0, stream>>>(qkvw, pw, w1, w2, wqkvT, projT, w1T, w2T);
  ln1_kernel<<<32768, 256, 0, stream>>>(x, n1g, n1b, hw);
  attn_kernel<<<2048, 512, 0, stream>>>(hw, wqkvT, qkvb, rpb);
  proj_kernel<<<2048, 256, 0, stream>>>(hw, projT, pb, x, out);
  mlp_kernel<<<2048, 512, 0, stream>>>(out, n2g, n2b, w1T, b1, w2T, b2);
}

// Round 6
// 541.526 us; speedup vs baseline: 1.7805x; 1.7805x over previous
//
#include <hip/hip_runtime.h>
#include <math.h>

typedef float f32x4 __attribute__((ext_vector_type(4)));
typedef short short8 __attribute__((ext_vector_type(8)));
typedef unsigned short u16;

#define BB 32
#define CC 192
#define HEADS 6
#define NN 64
#define HID 768
#define NTOK (BB * 64 * 64)
#define SCALE 0.17677669529663687f

#define MFMA(a, b, c) __builtin_amdgcn_mfma_f32_16x16x32_bf16(a, b, c, 0, 0, 0)

__device__ __forceinline__ u16 f2bf(float f) {
  union { float f; unsigned int u; } cv;
  cv.f = f;
  unsigned int u = cv.u;
  u += 0x7fffu + ((u >> 16) & 1u);
  return (u16)(u >> 16);
}

__device__ __forceinline__ f32x4 vzero() {
  f32x4 v;
  v[0] = 0.f; v[1] = 0.f; v[2] = 0.f; v[3] = 0.f;
  return v;
}

// A-style fragment read from swizzled LDS bf16 matrix. pitch in elements.
__device__ __forceinline__ short8 ldsA(const u16* M, int pitch, int r0, int k0, int lane) {
  const int r = r0 + (lane & 15);
  const int cb = ((k0 + ((lane >> 4) << 3)) << 1) ^ ((r & 7) << 4);
  return *(const short8*)(M + r * pitch + (cb >> 1));
}

// B fragment from global K-contiguous (transposed) bf16 weight [N][K].
__device__ __forceinline__ short8 glbB(const u16* W, int pitch, int n0, int k0, int lane) {
  const int n = n0 + (lane & 15);
  return *(const short8*)(W + (size_t)n * pitch + k0 + ((lane >> 4) << 3));
}

// ---------------------------------------------------------------------------
// K0: convert + transpose weights to bf16 K-contiguous tables in ws
// ---------------------------------------------------------------------------
__global__ __launch_bounds__(256) void prep_kernel(
    const float* __restrict__ qkvw, const float* __restrict__ pw,
    const float* __restrict__ w1, const float* __restrict__ w2,
    u16* __restrict__ wqkvT, u16* __restrict__ projT,
    u16* __restrict__ w1T, u16* __restrict__ w2T) {
  const int id = blockIdx.x * 256 + threadIdx.x;
  if (id < 576 * 192) { const int n = id / 192, k = id - n * 192; wqkvT[id] = f2bf(qkvw[k * 576 + n]); }
  if (id < 192 * 192) { const int n = id / 192, k = id - n * 192; projT[id] = f2bf(pw[k * 192 + n]); }
  if (id < 768 * 192) { const int n = id / 192, k = id - n * 192; w1T[id] = f2bf(w1[k * 768 + n]); }
  if (id < 192 * 768) { const int n = id / 768, k = id - n * 768; w2T[id] = f2bf(w2[k * 192 + n]); }
}

// ---------------------------------------------------------------------------
// K1: LN1 + cyclic shift (-4,-4) + window partition -> hw bf16 (B*nW, 64, 192)
// ---------------------------------------------------------------------------
__global__ __launch_bounds__(256) void ln1_kernel(
    const float* __restrict__ x, const float* __restrict__ gamma,
    const float* __restrict__ beta, u16* __restrict__ hw) {
  const int gid = blockIdx.x * blockDim.x + threadIdx.x;
  const int T = gid >> 6;
  const int lane = threadIdx.x & 63;
  if (T >= NTOK) return;
  const int g = T >> 6;
  const int n = T & 63;
  const int b = g >> 6;
  const int w = g & 63;
  const int wr = w >> 3, wc = w & 7;
  const int sr = ((wr << 3) + (n >> 3) + 4) & 63;
  const int sc = ((wc << 3) + (n & 7) + 4) & 63;
  const float* xp = x + ((size_t)b * 4096 + sr * 64 + sc) * CC;
  const float v0 = xp[lane], v1 = xp[lane + 64], v2 = xp[lane + 128];
  float s = v0 + v1 + v2;
  float sq = v0 * v0 + v1 * v1 + v2 * v2;
#pragma unroll
  for (int off = 1; off < 64; off <<= 1) {
    s += __shfl_xor(s, off);
    sq += __shfl_xor(sq, off);
  }
  const float mean = s * (1.0f / 192.0f);
  const float var = sq * (1.0f / 192.0f) - mean * mean;
  const float rstd = rsqrtf(var + 1e-5f);
  u16* op = hw + (size_t)T * CC;
  op[lane]       = f2bf((v0 - mean) * rstd * gamma[lane]       + beta[lane]);
  op[lane + 64]  = f2bf((v1 - mean) * rstd * gamma[lane + 64]  + beta[lane + 64]);
  op[lane + 128] = f2bf((v2 - mean) * rstd * gamma[lane + 128] + beta[lane + 128]);
}

// ---------------------------------------------------------------------------
// K2: windowed attention, MFMA. 1 block = 1 window, 8 waves.
// In-register softmax; per-head loop is barrier-free.
// ---------------------------------------------------------------------------
__global__ __launch_bounds__(512) void attn_kernel(
    u16* __restrict__ hw, const u16* __restrict__ wqkvT,
    const float* __restrict__ qkvb, const float* __restrict__ rpb) {
  __shared__ u16 Xs[64 * 192];
  __shared__ u16 Qs[64 * 192];
  __shared__ u16 Ks[64 * 192];
  __shared__ u16 Vt[192 * 64];     // [channel][token]
  __shared__ u16 Pb[2][64 * 64];

  const int g = blockIdx.x;
  const int t = threadIdx.x;
  const int w = t >> 6;
  const int lane = t & 63;
  const int wr = (g >> 3) & 7, wc = g & 7;
  u16* win = hw + (size_t)g * (64 * 192);

  // stage window into Xs (swizzled), 16B units
#pragma unroll
  for (int u = 0; u < 3; ++u) {
    const int d = (t * 3 + u) << 4;
    const int row = d / 384;
    const int cb = d - row * 384;
    const short8 v = *(const short8*)((const char*)win + d);
    *(short8*)((char*)Xs + row * 384 + (cb ^ ((row & 7) << 4))) = v;
  }
  __syncthreads();

  // ---- QKV GEMM: 64x192 @ 192x576 ----
  const int ntbeg = (w < 4) ? w * 5 : 20 + (w - 4) * 4;
  const int ntcnt = (w < 4) ? 5 : 4;
  f32x4 acc[5][4];
#pragma unroll
  for (int p = 0; p < 5; ++p)
#pragma unroll
    for (int m = 0; m < 4; ++m) acc[p][m] = vzero();
#pragma unroll
  for (int kk = 0; kk < 6; ++kk) {
    const int k0 = kk << 5;
    short8 a[4];
#pragma unroll
    for (int m = 0; m < 4; ++m) a[m] = ldsA(Xs, 192, m << 4, k0, lane);
#pragma unroll
    for (int p = 0; p < 5; ++p) {
      int nt = ntbeg + p;
      if (nt > 35) nt = 35;  // waves 4-7 duplicate last tile (discarded)
      const short8 b = glbB(wqkvT, 192, nt << 4, k0, lane);
#pragma unroll
      for (int m = 0; m < 4; ++m) acc[p][m] = MFMA(a[m], b, acc[p][m]);
    }
  }
#pragma unroll
  for (int p = 0; p < 5; ++p) {
    if (p < ntcnt) {
      const int cg = ((ntbeg + p) << 4) + (lane & 15);
      const float bias = qkvb[cg];
#pragma unroll
      for (int m = 0; m < 4; ++m) {
#pragma unroll
        for (int i = 0; i < 4; ++i) {
          const int r = (m << 4) + ((lane >> 4) << 2) + i;
          const float val = acc[p][m][i] + bias;
          if (cg < 192) {
            const int cb = (cg << 1) ^ ((r & 7) << 4);
            Qs[r * 192 + (cb >> 1)] = f2bf(val * SCALE);
          } else if (cg < 384) {
            const int cb = ((cg - 192) << 1) ^ ((r & 7) << 4);
            Ks[r * 192 + (cb >> 1)] = f2bf(val);
          } else {
            const int vc = cg - 384;
            const int cb = (r << 1) ^ ((vc & 7) << 4);
            Vt[vc * 64 + (cb >> 1)] = f2bf(val);
          }
        }
      }
    }
  }
  __syncthreads();

  // ---- per-head: scores -> in-reg softmax -> PV. wave = (s, mt). ----
  const int s = w >> 2;
  const int mt = w & 3;
  u16* P = Pb[s];
  const int cbase = lane & 15;
  for (int hh = 0; hh < 3; ++hh) {
    const int h = s * 3 + hh;
    const short8 aq = ldsA(Qs, 192, mt << 4, h << 5, lane);
    f32x4 d[4];
#pragma unroll
    for (int kb = 0; kb < 4; ++kb) {
      const short8 bk = ldsA(Ks, 192, kb << 4, h << 5, lane);
      d[kb] = MFMA(aq, bk, vzero());
      const int c = (kb << 4) + cbase;
      const int i2 = c >> 3, j2 = c & 7;
      const int gr2 = (wr << 3) + i2, gc2 = (wc << 3) + j2;
      const int lab2 = (gr2 < 56 ? 0 : (gr2 < 60 ? 1 : 2)) * 3 +
                       (gc2 < 56 ? 0 : (gc2 < 60 ? 1 : 2));
#pragma unroll
      for (int i = 0; i < 4; ++i) {
        const int r = (mt << 4) + ((lane >> 4) << 2) + i;
        const int i1 = r >> 3, j1 = r & 7;
        const int gr1 = (wr << 3) + i1, gc1 = (wc << 3) + j1;
        const int lab1 = (gr1 < 56 ? 0 : (gr1 < 60 ? 1 : 2)) * 3 +
                         (gc1 < 56 ? 0 : (gc1 < 60 ? 1 : 2));
        float v = d[kb][i] + rpb[((i1 - i2 + 7) * 15 + (j1 - j2 + 7)) * HEADS + h];
        if (lab1 != lab2) v -= 100.f;
        d[kb][i] = v;
      }
    }
    // in-register softmax: row r spread over the 16-lane group (lane&15)
    float mx[4], sum[4];
#pragma unroll
    for (int i = 0; i < 4; ++i) {
      mx[i] = fmaxf(fmaxf(d[0][i], d[1][i]), fmaxf(d[2][i], d[3][i]));
    }
#pragma unroll
    for (int msk = 1; msk < 16; msk <<= 1) {
#pragma unroll
      for (int i = 0; i < 4; ++i) mx[i] = fmaxf(mx[i], __shfl_xor(mx[i], msk));
    }
#pragma unroll
    for (int i = 0; i < 4; ++i) sum[i] = 0.f;
#pragma unroll
    for (int kb = 0; kb < 4; ++kb) {
#pragma unroll
      for (int i = 0; i < 4; ++i) {
        const float e = __expf(d[kb][i] - mx[i]);
        d[kb][i] = e;
        sum[i] += e;
      }
    }
#pragma unroll
    for (int msk = 1; msk < 16; msk <<= 1) {
#pragma unroll
      for (int i = 0; i < 4; ++i) sum[i] += __shfl_xor(sum[i], msk);
    }
#pragma unroll
    for (int kb = 0; kb < 4; ++kb) {
      const int c = (kb << 4) + cbase;
#pragma unroll
      for (int i = 0; i < 4; ++i) {
        const int r = (mt << 4) + ((lane >> 4) << 2) + i;
        const int cb = (c << 1) ^ ((r & 7) << 4);
        P[r * 64 + (cb >> 1)] = f2bf(d[kb][i] / sum[i]);
      }
    }
    // PV: O rows 16mt..+15, cols h*32 + nb*16 (reads only this wave's P rows)
#pragma unroll
    for (int nb = 0; nb < 2; ++nb) {
      f32x4 o = vzero();
#pragma unroll
      for (int ks = 0; ks < 2; ++ks) {
        const short8 ap = ldsA(P, 64, mt << 4, ks << 5, lane);
        const short8 bv = ldsA(Vt, 64, (h << 5) + (nb << 4), ks << 5, lane);
        o = MFMA(ap, bv, o);
      }
      const int c = (h << 5) + (nb << 4) + (lane & 15);
#pragma unroll
      for (int i = 0; i < 4; ++i) {
        const int r = (mt << 4) + ((lane >> 4) << 2) + i;
        win[r * 192 + c] = f2bf(o[i]);
      }
    }
  }
}

// ---------------------------------------------------------------------------
// K3: proj GEMM + bias + reverse shift scatter + residual -> out (fp32)
// ---------------------------------------------------------------------------
__global__ __launch_bounds__(256) void proj_kernel(
    const u16* __restrict__ hw, const u16* __restrict__ projT,
    const float* __restrict__ pb, const float* __restrict__ x,
    float* __restrict__ out) {
  __shared__ u16 Os[64 * 192];
  const int g = blockIdx.x;
  const int t = threadIdx.x;
  const int w = t >> 6;
  const int lane = t & 63;
  const int b_ = g >> 6;
  const int wr = (g >> 3) & 7, wc = g & 7;
  const u16* win = hw + (size_t)g * (64 * 192);
#pragma unroll
  for (int u = 0; u < 6; ++u) {
    const int d = (t * 6 + u) << 4;
    const int row = d / 384;
    const int cb = d - row * 384;
    const short8 v = *(const short8*)((const char*)win + d);
    *(short8*)((char*)Os + row * 384 + (cb ^ ((row & 7) << 4))) = v;
  }
  __syncthreads();
#pragma unroll
  for (int gi = 0; gi < 2; ++gi) {
    f32x4 acc[6];
#pragma unroll
    for (int p = 0; p < 6; ++p) acc[p] = vzero();
#pragma unroll
    for (int kk = 0; kk < 6; ++kk) {
      const int k0 = kk << 5;
      const short8 a = ldsA(Os, 192, w << 4, k0, lane);
#pragma unroll
      for (int p = 0; p < 6; ++p) {
        const short8 b = glbB(projT, 192, (gi * 6 + p) << 4, k0, lane);
        acc[p] = MFMA(a, b, acc[p]);
      }
    }
#pragma unroll
    for (int p = 0; p < 6; ++p) {
      const int col = ((gi * 6 + p) << 4) + (lane & 15);
      const float bias = pb[col];
#pragma unroll
      for (int i = 0; i < 4; ++i) {
        const int r = (w << 4) + ((lane >> 4) << 2) + i;
        const int dr = ((wr << 3) + (r >> 3) + 4) & 63;
        const int dc = ((wc << 3) + (r & 7) + 4) & 63;
        const size_t dst = ((size_t)b_ * 4096 + dr * 64 + dc) * 192 + col;
        out[dst] = x[dst] + acc[p][i] + bias;
      }
    }
  }
}

// ---------------------------------------------------------------------------
// K4: LN2 + fc1 + GELU + fc2 + residual. 64 tokens/block, 8 waves.
// Weights LDS-staged (double-buffered 12 KB slices, T14 issue-early/write-
// late); 4 phases of 192 hidden cols; Hs 24 KB; total LDS 72 KB -> 2 blk/CU.
// ---------------------------------------------------------------------------
__global__ __launch_bounds__(512, 4) void mlp_kernel(
    float* __restrict__ out, const float* __restrict__ g2,
    const float* __restrict__ bn2, const u16* __restrict__ w1T,
    const float* __restrict__ b1, const u16* __restrict__ w2T,
    const float* __restrict__ bo) {
  __shared__ u16 Xn[64 * 192];          // swizzled, pitch 192
  __shared__ u16 Hs[64 * 192];          // swizzled, pitch 192 (per-phase)
  __shared__ u16 Wb[2][4 * 192 * 8];    // [buf][kc][n][8] = 12 KB each
  const size_t T0 = (size_t)blockIdx.x * 64;
  const int t = threadIdx.x;
  const int w = t >> 6;
  const int lane = t & 63;
  const int mt = w & 3;
  const int half = w >> 2;

  {  // LN2: 8 lanes per token, 24 ch each
    const int tok = t >> 3;
    const int ch0 = (t & 7) * 24;
    const float* xp = out + (T0 + tok) * 192 + ch0;
    float v[24];
    float s = 0.f, sq = 0.f;
#pragma unroll
    for (int q = 0; q < 6; ++q) {
      const float4 f4 = *(const float4*)(xp + q * 4);
      v[q * 4 + 0] = f4.x; v[q * 4 + 1] = f4.y;
      v[q * 4 + 2] = f4.z; v[q * 4 + 3] = f4.w;
    }
#pragma unroll
    for (int q = 0; q < 24; ++q) { s += v[q]; sq += v[q] * v[q]; }
#pragma unroll
    for (int msk = 1; msk < 8; msk <<= 1) {
      s += __shfl_xor(s, msk);
      sq += __shfl_xor(sq, msk);
    }
    const float mean = s * (1.f / 192.f);
    const float var = sq * (1.f / 192.f) - mean * mean;
    const float rstd = rsqrtf(var + 1e-5f);
#pragma unroll
    for (int q = 0; q < 12; ++q) {
      const int ch = ch0 + q * 2;
      const float a0 = (v[q * 2] - mean) * rstd * g2[ch] + bn2[ch];
      const float a1 = (v[q * 2 + 1] - mean) * rstd * g2[ch + 1] + bn2[ch + 1];
      const unsigned int pk = (unsigned int)f2bf(a0) | ((unsigned int)f2bf(a1) << 16);
      const int cb = (ch << 1) ^ ((tok & 7) << 4);
      *(unsigned int*)&Xn[tok * 192 + (cb >> 1)] = pk;
    }
  }

  // stage helpers: slice = [192 n][32 k] of a [N][pitch] bf16 table,
  // stored in Wb as [kc 0..3][n 0..191][8 elems]
  short8 sr0, sr1;
  const int sn0 = t >> 2, skc0 = t & 3;              // chunk id = t
  const int sn1 = (512 + t) >> 2, skc1 = (512 + t) & 3;  // chunk id = 512+t (t<256)
  const bool st1 = (t < 256);

  f32x4 acc2[6];
#pragma unroll
  for (int p = 0; p < 6; ++p) acc2[p] = vzero();
  int cur = 0;

  __syncthreads();  // Xn ready

  for (int ph = 0; ph < 4; ++ph) {
    const u16* w1p = w1T + ph * 192 * 192;  // rows = hidden cols of this phase
    // ---- fc1: 192 cols, K=192 ----
    f32x4 acc1[6];
#pragma unroll
    for (int p = 0; p < 6; ++p) acc1[p] = vzero();
    // prologue stage kk=0
    sr0 = *(const short8*)(w1p + (size_t)sn0 * 192 + skc0 * 8);
    if (st1) sr1 = *(const short8*)(w1p + (size_t)sn1 * 192 + skc1 * 8);
    *(short8*)(Wb[cur] + (skc0 * 192 + sn0) * 8) = sr0;
    if (st1) *(short8*)(Wb[cur] + (skc1 * 192 + sn1) * 8) = sr1;
    __syncthreads();
#pragma unroll
    for (int kk = 0; kk < 6; ++kk) {
      if (kk < 5) {  // issue next-slice loads early
        const int k0n = (kk + 1) << 5;
        sr0 = *(const short8*)(w1p + (size_t)sn0 * 192 + k0n + skc0 * 8);
        if (st1) sr1 = *(const short8*)(w1p + (size_t)sn1 * 192 + k0n + skc1 * 8);
      }
      const short8 a = ldsA(Xn, 192, mt << 4, kk << 5, lane);
#pragma unroll
      for (int p = 0; p < 6; ++p) {
        const short8 b = *(const short8*)(
            Wb[cur] + (((lane >> 4) * 192) + ((half * 6 + p) << 4) + (lane & 15)) * 8);
        acc1[p] = MFMA(a, b, acc1[p]);
      }
      if (kk < 5) {  // write next slice late
        *(short8*)(Wb[cur ^ 1] + (skc0 * 192 + sn0) * 8) = sr0;
        if (st1) *(short8*)(Wb[cur ^ 1] + (skc1 * 192 + sn1) * 8) = sr1;
      }
      __syncthreads();
      cur ^= 1;
    }
    // ---- GELU -> Hs; overlap fc2 kk2=0 stage load ----
    sr0 = *(const short8*)(w2T + (size_t)sn0 * 768 + ph * 192 + skc0 * 8);
    if (st1) sr1 = *(const short8*)(w2T + (size_t)sn1 * 768 + ph * 192 + skc1 * 8);
#pragma unroll
    for (int p = 0; p < 6; ++p) {
      const int lcol = ((half * 6 + p) << 4) + (lane & 15);
      const float bias = b1[ph * 192 + lcol];
#pragma unroll
      for (int i = 0; i < 4; ++i) {
        const int r = (mt << 4) + ((lane >> 4) << 2) + i;
        const float hv = acc1[p][i] + bias;
        const float ge = 0.5f * hv * (1.0f + erff(hv * 0.70710678118654752f));
        const int cb = (lcol << 1) ^ ((r & 7) << 4);
        Hs[r * 192 + (cb >> 1)] = f2bf(ge);
      }
    }
    *(short8*)(Wb[cur] + (skc0 * 192 + sn0) * 8) = sr0;
    if (st1) *(short8*)(Wb[cur] + (skc1 * 192 + sn1) * 8) = sr1;
    __syncthreads();
    // ---- fc2 partial: K slice [ph*192, +192), acc2 persists ----
#pragma unroll
    for (int kk = 0; kk < 6; ++kk) {
      if (kk < 5) {
        const int k0n = ph * 192 + ((kk + 1) << 5);
        sr0 = *(const short8*)(w2T + (size_t)sn0 * 768 + k0n + skc0 * 8);
        if (st1) sr1 = *(const short8*)(w2T + (size_t)sn1 * 768 + k0n + skc1 * 8);
      }
      const short8 a = ldsA(Hs, 192, mt << 4, kk << 5, lane);
#pragma unroll
      for (int p = 0; p < 6; ++p) {
        const short8 b = *(const short8*)(
            Wb[cur] + (((lane >> 4) * 192) + ((half * 6 + p) << 4) + (lane & 15)) * 8);
        acc2[p] = MFMA(a, b, acc2[p]);
      }
      if (kk < 5) {
        *(short8*)(Wb[cur ^ 1] + (skc0 * 192 + sn0) * 8) = sr0;
        if (st1) *(short8*)(Wb[cur ^ 1] + (skc1 * 192 + sn1) * 8) = sr1;
      }
      __syncthreads();
      cur ^= 1;
    }
  }

  // ---- fc2 epilogue + residual ----
#pragma unroll
  for (int p = 0; p < 6; ++p) {
    const int col = ((half * 6 + p) << 4) + (lane & 15);
    const float bias = bo[col];
#pragma unroll
    for (int i = 0; i < 4; ++i) {
      const int r = (mt << 4) + ((lane >> 4) << 2) + i;
      float* op = out + (T0 + r) * 192 + col;
      *op = *op + acc2[p][i] + bias;
    }
  }
}

// ---------------------------------------------------------------------------
extern "C" void kernel_launch(void* const* d_in, const int* in_sizes, int n_in,
                              void* d_out, int out_size, void* d_ws, size_t ws_size,
                              hipStream_t stream) {
  const float* x    = (const float*)d_in[0];
  const float* n1g  = (const float*)d_in[1];
  const float* n1b  = (const float*)d_in[2];
  const float* qkvw = (const float*)d_in[3];
  const float* qkvb = (const float*)d_in[4];
  const float* rpb  = (const float*)d_in[5];
  const float* pw   = (const float*)d_in[6];
  const float* pb   = (const float*)d_in[7];
  const float* n2g  = (const float*)d_in[8];
  const float* n2b  = (const float*)d_in[9];
  const float* w1   = (const float*)d_in[10];
  const float* b1   = (const float*)d_in[11];
  const float* w2   = (const float*)d_in[12];
  const float* b2   = (const float*)d_in[13];
  float* out = (float*)d_out;

  u16* hw    = (u16*)d_ws;                       // 131072*192 bf16 = 50.3 MB
  u16* wqkvT = hw + (size_t)131072 * 192;        // [576][192]
  u16* projT = wqkvT + 576 * 192;                // [192][192]
  u16* w1T   = projT + 192 * 192;                // [768][192]
  u16* w2T   = w1T + 768 * 192;                  // [192][768]

  prep_kernel<<<576, 256, 0, stream>>>(qkvw, pw, w1, w2, wqkvT, projT, w1T, w2T);
  ln1_kernel<<<32768, 256, 0, stream>>>(x, n1g, n1b, hw);
  attn_kernel<<<2048, 512, 0, stream>>>(hw, wqkvT, qkvb, rpb);
  proj_kernel<<<2048, 256, 0, stream>>>(hw, projT, pb, x, out);
  mlp_kernel<<<2048, 512, 0, stream>>>(out, n2g, n2b, w1T, b1, w2T, b2);
}